// Round 1
// baseline (579.262 us; speedup 1.0000x reference)
//
#include <hip/hip_runtime.h>

#define T_LEN 2048
#define B_LEN 512
#define C_LEN 64

// ---------------------------------------------------------------------------
// Kernel 1: tiny precompute (1 block).
//  - inclusive scan of warp_noise*(0.2/T) over T=2048 (1024 threads, 2 el/thr)
//  - normalize per reference: warp = (S[t]-S[0]) / (S[T-1]-S[0] + 1e-8)
//  - i0[t] = clip(floor(pos),0,T-2), frac[t] = pos - i0
//  - ca[b], sa[b] = cos/sin(angle_u[b]*2pi - pi)
// ---------------------------------------------------------------------------
__global__ __launch_bounds__(1024) void precomp_kernel(
    const float* __restrict__ warp_noise,
    const float* __restrict__ angle_u,
    int*   __restrict__ ws_i0,    // [T]
    float* __restrict__ ws_frac,  // [T]
    float* __restrict__ ws_ca,    // [B]
    float* __restrict__ ws_sa)    // [B]
{
    __shared__ float S[T_LEN];
    __shared__ float P[1024];
    const int i = threadIdx.x;
    const float k = 0.2f / 2048.0f;   // TW_SIGMA / T

    float e0 = warp_noise[2 * i]     * k;
    float e1 = warp_noise[2 * i + 1] * k;
    float l1 = e0 + e1;               // local inclusive sum of the pair
    P[i] = l1;
    __syncthreads();

    // Hillis-Steele inclusive scan over 1024 pair-sums
    for (int d = 1; d < 1024; d <<= 1) {
        float v = (i >= d) ? P[i - d] : 0.0f;
        __syncthreads();
        P[i] += v;
        __syncthreads();
    }

    float excl = P[i] - l1;           // exclusive prefix for this pair
    S[2 * i]     = excl + e0;         // inclusive cumsum values
    S[2 * i + 1] = excl + l1;
    __syncthreads();

    const float s0    = S[0];
    const float denom = (S[T_LEN - 1] - s0) + 1e-8f;

    for (int t = i; t < T_LEN; t += 1024) {
        float w      = (S[t] - s0) / denom;
        float t_orig = (float)t / (float)(T_LEN - 1);
        float tw     = t_orig + w * 0.2f;
        tw = fminf(fmaxf(tw, 0.0f), 1.0f);
        float pos = tw * (float)(T_LEN - 1);
        int idx0 = (int)floorf(pos);
        idx0 = min(max(idx0, 0), T_LEN - 2);
        ws_i0[t]   = idx0;
        ws_frac[t] = pos - (float)idx0;
    }

    if (i < B_LEN) {
        float ang = angle_u[i] * 6.28318530717958647692f - 3.14159265358979323846f;
        ws_ca[i] = cosf(ang);
        ws_sa[i] = sinf(ang);
    }
}

// ---------------------------------------------------------------------------
// Kernel 2: fused jitter + scale + warp-gather-interp + rotate + mask.
// One float4 (4 channels) per thread; 16 threads per row; 16 rows (t) per
// block for one b -> gathered source rows overlap heavily within a block
// (i0 slope ~= 1) so the 2x logical read collapses to ~1x HBM via L1/L2.
// ---------------------------------------------------------------------------
__global__ __launch_bounds__(256) void augment_kernel(
    const float* __restrict__ x,
    const float* __restrict__ noise,
    const float* __restrict__ scale_u,
    const float* __restrict__ chmask_u,
    const int*   __restrict__ ws_i0,
    const float* __restrict__ ws_frac,
    const float* __restrict__ ws_ca,
    const float* __restrict__ ws_sa,
    float* __restrict__ out)
{
    const int tid = threadIdx.x;
    const int c4  = tid & 15;                         // which float4 of the row
    const int b   = blockIdx.x >> 7;                  // 128 t-chunks per batch
    const int t   = ((blockIdx.x & 127) << 4) + (tid >> 4);

    const int   i0 = ws_i0[t];
    const float fr = ws_frac[t];
    const float scale = 0.9f + scale_u[0] * 0.2f;
    // scale is scalar -> commutes with the linear interp; fold into weights
    const float w0 = scale * (1.0f - fr);
    const float w1 = scale * fr;

    const float4* __restrict__ x4 = (const float4*)x;
    const float4* __restrict__ n4 = (const float4*)noise;

    const int src0 = (b * T_LEN + i0) * (C_LEN / 4) + c4;
    float4 a0 = x4[src0];
    float4 a1 = x4[src0 + (C_LEN / 4)];   // row i0+1 (i0 <= T-2 guaranteed)
    float4 q0 = n4[src0];
    float4 q1 = n4[src0 + (C_LEN / 4)];

    float4 v;
    v.x = (a0.x + q0.x * 0.01f) * w0 + (a1.x + q1.x * 0.01f) * w1;
    v.y = (a0.y + q0.y * 0.01f) * w0 + (a1.y + q1.y * 0.01f) * w1;
    v.z = (a0.z + q0.z * 0.01f) * w0 + (a1.z + q1.z * 0.01f) * w1;
    v.w = (a0.w + q0.w * 0.01f) * w0 + (a1.w + q1.w * 0.01f) * w1;

    // rotation of channels 0,1 — both live in the c4==0 float4 (lane-local)
    if (c4 == 0) {
        float ca = ws_ca[b], sa = ws_sa[b];
        float r0 = ca * v.x - sa * v.y;
        float r1 = sa * v.x + ca * v.y;
        v.x = r0; v.y = r1;
    }

    // channel dropout: keep if u > 0.1
    float4 cm = ((const float4*)chmask_u)[c4];
    v.x = (cm.x > 0.1f) ? v.x : 0.0f;
    v.y = (cm.y > 0.1f) ? v.y : 0.0f;
    v.z = (cm.z > 0.1f) ? v.z : 0.0f;
    v.w = (cm.w > 0.1f) ? v.w : 0.0f;

    ((float4*)out)[(b * T_LEN + t) * (C_LEN / 4) + c4] = v;
}

extern "C" void kernel_launch(void* const* d_in, const int* in_sizes, int n_in,
                              void* d_out, int out_size, void* d_ws, size_t ws_size,
                              hipStream_t stream) {
    const float* x          = (const float*)d_in[0];
    const float* noise      = (const float*)d_in[1];
    const float* scale_u    = (const float*)d_in[2];
    const float* warp_noise = (const float*)d_in[3];
    const float* angle_u    = (const float*)d_in[4];
    const float* chmask_u   = (const float*)d_in[5];
    float* out = (float*)d_out;

    // ws layout (20.5 KiB total):
    char*  ws      = (char*)d_ws;
    int*   ws_i0   = (int*)  ws;              // [2048] ints  :  8192 B
    float* ws_frac = (float*)(ws + 8192);     // [2048] floats:  8192 B
    float* ws_ca   = (float*)(ws + 16384);    // [512]  floats:  2048 B
    float* ws_sa   = (float*)(ws + 18432);    // [512]  floats:  2048 B

    hipLaunchKernelGGL(precomp_kernel, dim3(1), dim3(1024), 0, stream,
                       warp_noise, angle_u, ws_i0, ws_frac, ws_ca, ws_sa);

    hipLaunchKernelGGL(augment_kernel, dim3((B_LEN * T_LEN) / 16), dim3(256), 0, stream,
                       x, noise, scale_u, chmask_u, ws_i0, ws_frac, ws_ca, ws_sa, out);
}